// Round 2
// baseline (1939.418 us; speedup 1.0000x reference)
//
#include <hip/hip_runtime.h>
#include <hip/hip_fp16.h>

#define B_SZ 4
#define T_SEQ 2048
#define NH 16
#define HD 64
#define DMODEL 1024
#define MTOT (B_SZ * T_SEQ)   // 8192

typedef __bf16 bf16x8 __attribute__((ext_vector_type(8)));
typedef float f32x4 __attribute__((ext_vector_type(4)));

__device__ __forceinline__ unsigned short f2bf(float f) {
    union { float f; unsigned int i; } c; c.f = f;
    unsigned int u = c.i;
    u += 0x7fffu + ((u >> 16) & 1u);   // round-to-nearest-even
    return (unsigned short)(u >> 16);
}
__device__ __forceinline__ float sigm(float x) { return 1.f / (1.f + __expf(-x)); }

// ---------------------------------------------------------------- LayerNorm
// fp32 in -> bf16 out
__global__ __launch_bounds__(256, 1) void k_ln(const float* __restrict__ x,
                                               const float* __restrict__ lnw,
                                               const float* __restrict__ lnb,
                                               unsigned short* __restrict__ xn) {
    const int m = blockIdx.x;
    const int t = threadIdx.x;
    float4 xv = ((const float4*)(x + (size_t)m * DMODEL))[t];
    float s = xv.x + xv.y + xv.z + xv.w;
    float s2 = xv.x * xv.x + xv.y * xv.y + xv.z * xv.z + xv.w * xv.w;
#pragma unroll
    for (int off = 32; off >= 1; off >>= 1) {
        s += __shfl_xor(s, off);
        s2 += __shfl_xor(s2, off);
    }
    __shared__ float red[8];
    const int wid = t >> 6;
    if ((t & 63) == 0) { red[wid] = s; red[4 + wid] = s2; }
    __syncthreads();
    if (t == 0) {
        float su = red[0] + red[1] + red[2] + red[3];
        float sq = red[4] + red[5] + red[6] + red[7];
        float mu = su * (1.f / DMODEL);
        float var = sq * (1.f / DMODEL) - mu * mu;
        red[0] = mu;
        red[1] = rsqrtf(var + 1e-5f);
    }
    __syncthreads();
    float mu = red[0], rstd = red[1];
    float4 w4 = ((const float4*)lnw)[t];
    float4 b4 = ((const float4*)lnb)[t];
    ushort4 o;
    o.x = f2bf((xv.x - mu) * rstd * w4.x + b4.x);
    o.y = f2bf((xv.y - mu) * rstd * w4.y + b4.y);
    o.z = f2bf((xv.z - mu) * rstd * w4.z + b4.z);
    o.w = f2bf((xv.w - mu) * rstd * w4.w + b4.w);
    ((ushort4*)(xn + (size_t)m * DMODEL))[t] = o;
}

__device__ __forceinline__ void store_bf8(unsigned short* p, float4 a, float4 b) {
    ushort4 lo, hi;
    lo.x = f2bf(a.x); lo.y = f2bf(a.y); lo.z = f2bf(a.z); lo.w = f2bf(a.w);
    hi.x = f2bf(b.x); hi.y = f2bf(b.y); hi.z = f2bf(b.z); hi.w = f2bf(b.w);
    *(ushort4*)p = lo;
    *(ushort4*)(p + 4) = hi;
}

// ------------------------------------------------- 128x128 bf16 MFMA tile GEMM
// A: (M,K) row-major bf16, Bw: (N,K) row-major FP32 (converted to bf16 while
// staging to LDS). Computes A @ Bw^T in fp32 accumulators.
template <int KDIM>
__device__ __forceinline__ void gemm128(const unsigned short* __restrict__ A,
                                        const float* __restrict__ Bw,
                                        int m0, int n0, f32x4 acc[4][4]) {
    __shared__ __align__(16) unsigned short sA[128 * 40];  // 32 + 8 pad
    __shared__ __align__(16) unsigned short sB[128 * 40];

    const int t = threadIdx.x;
    const int lane = t & 63;
    const int wv = t >> 6;
    const int wm = wv >> 1, wn = wv & 1;
    const int ml = lane & 15, kq = lane >> 4;

#pragma unroll
    for (int i = 0; i < 4; i++)
#pragma unroll
        for (int j = 0; j < 4; j++) {
            f32x4 z; z[0] = 0.f; z[1] = 0.f; z[2] = 0.f; z[3] = 0.f;
            acc[i][j] = z;
        }

    const int r0 = t >> 2, q0 = t & 3;   // rows 0..63
    const int r1 = r0 + 64;              // rows 64..127, same q
    const unsigned short* pA = A + (size_t)m0 * KDIM;
    const float* pB = Bw + (size_t)n0 * KDIM;

    uint4 ra0 = *(const uint4*)(pA + (size_t)r0 * KDIM + q0 * 8);
    uint4 ra1 = *(const uint4*)(pA + (size_t)r1 * KDIM + q0 * 8);
    float4 rb0a = *(const float4*)(pB + (size_t)r0 * KDIM + q0 * 8);
    float4 rb0b = *(const float4*)(pB + (size_t)r0 * KDIM + q0 * 8 + 4);
    float4 rb1a = *(const float4*)(pB + (size_t)r1 * KDIM + q0 * 8);
    float4 rb1b = *(const float4*)(pB + (size_t)r1 * KDIM + q0 * 8 + 4);

    for (int kb = 0; kb < KDIM / 32; kb++) {
        __syncthreads();
        *(uint4*)&sA[r0 * 40 + q0 * 8] = ra0;
        *(uint4*)&sA[r1 * 40 + q0 * 8] = ra1;
        store_bf8(&sB[r0 * 40 + q0 * 8], rb0a, rb0b);
        store_bf8(&sB[r1 * 40 + q0 * 8], rb1a, rb1b);
        __syncthreads();
        if (kb + 1 < KDIM / 32) {
            const unsigned short* nA = pA + (kb + 1) * 32;
            const float* nB = pB + (kb + 1) * 32;
            ra0 = *(const uint4*)(nA + (size_t)r0 * KDIM + q0 * 8);
            ra1 = *(const uint4*)(nA + (size_t)r1 * KDIM + q0 * 8);
            rb0a = *(const float4*)(nB + (size_t)r0 * KDIM + q0 * 8);
            rb0b = *(const float4*)(nB + (size_t)r0 * KDIM + q0 * 8 + 4);
            rb1a = *(const float4*)(nB + (size_t)r1 * KDIM + q0 * 8);
            rb1b = *(const float4*)(nB + (size_t)r1 * KDIM + q0 * 8 + 4);
        }
        bf16x8 af[4], bfr[4];
#pragma unroll
        for (int mt = 0; mt < 4; mt++)
            af[mt] = *(const bf16x8*)&sA[(wm * 64 + mt * 16 + ml) * 40 + kq * 8];
#pragma unroll
        for (int nt = 0; nt < 4; nt++)
            bfr[nt] = *(const bf16x8*)&sB[(wn * 64 + nt * 16 + ml) * 40 + kq * 8];
#pragma unroll
        for (int mt = 0; mt < 4; mt++)
#pragma unroll
            for (int nt = 0; nt < 4; nt++)
                acc[mt][nt] = __builtin_amdgcn_mfma_f32_16x16x32_bf16(af[mt], bfr[nt], acc[mt][nt], 0, 0, 0);
    }
}

// -------------------------------------------- fused 5-way projection GEMM
__global__ __launch_bounds__(256, 1) void k_proj(const unsigned short* __restrict__ xn,
                                                 const float* __restrict__ Wq,
                                                 const float* __restrict__ Wk,
                                                 const float* __restrict__ Wv,
                                                 const float* __restrict__ Wa,
                                                 const float* __restrict__ WaR,
                                                 const float* __restrict__ ba,
                                                 const float* __restrict__ baR,
                                                 __half* __restrict__ qo, __half* __restrict__ ko,
                                                 __half* __restrict__ vo, __half* __restrict__ ao,
                                                 __half* __restrict__ aRo) {
    const int m0 = blockIdx.x * 128;
    const int yt = blockIdx.y;
    const int widx = yt >> 3;
    const int n0 = (yt & 7) * 128;
    const float* W = widx == 0 ? Wq : widx == 1 ? Wk : widx == 2 ? Wv : widx == 3 ? Wa : WaR;
    f32x4 acc[4][4];
    gemm128<1024>(xn, W, m0, n0, acc);

    __half* outp = widx == 0 ? qo : widx == 1 ? ko : widx == 2 ? vo : widx == 3 ? ao : aRo;
    const float* bias = (widx == 3) ? ba : (widx == 4) ? baR : (const float*)0;
    const int lane = threadIdx.x & 63;
    const int wv = threadIdx.x >> 6;
    const int wm = wv >> 1, wn = wv & 1;
    const int ml = lane & 15, kq = lane >> 4;
#pragma unroll
    for (int mt = 0; mt < 4; mt++)
#pragma unroll
        for (int nt = 0; nt < 4; nt++) {
            const int rowg = m0 + wm * 64 + mt * 16 + kq * 4;
            const int colg = n0 + wn * 64 + nt * 16 + ml;
            float bval = bias ? bias[colg] : 0.f;
#pragma unroll
            for (int r = 0; r < 4; r++) {
                float v = acc[mt][nt][r];
                if (widx >= 3) v = sigm(v + bval);
                outp[(size_t)(rowg + r) * DMODEL + colg] = __float2half(v);
            }
        }
}

// --------------------------------------------------- beta/gamma skinny GEMM
__global__ __launch_bounds__(256, 1) void k_bg(const unsigned short* __restrict__ xn,
                                               const float* __restrict__ Wb,
                                               const float* __restrict__ bb,
                                               const float* __restrict__ Wg,
                                               const float* __restrict__ bg,
                                               float* __restrict__ betab,
                                               float* __restrict__ gammab) {
    const int m = blockIdx.x;
    const int t = threadIdx.x;
    const int h = t >> 4, seg = t & 15;
    const ushort4* xr = (const ushort4*)(xn + (size_t)m * DMODEL + seg * 64);
    const float4* wbr = (const float4*)(Wb + (size_t)h * DMODEL + seg * 64);
    const float4* wgr = (const float4*)(Wg + (size_t)h * DMODEL + seg * 64);
    float db = 0.f, dg = 0.f;
#pragma unroll
    for (int u = 0; u < 16; u++) {
        ushort4 a = xr[u];
        float4 w1 = wbr[u], w2 = wgr[u];
        union { unsigned int i; float f; } c0, c1, c2, c3;
        c0.i = ((unsigned int)a.x) << 16; c1.i = ((unsigned int)a.y) << 16;
        c2.i = ((unsigned int)a.z) << 16; c3.i = ((unsigned int)a.w) << 16;
        db += c0.f * w1.x + c1.f * w1.y + c2.f * w1.z + c3.f * w1.w;
        dg += c0.f * w2.x + c1.f * w2.y + c2.f * w2.z + c3.f * w2.w;
    }
#pragma unroll
    for (int off = 1; off < 16; off <<= 1) {
        db += __shfl_xor(db, off);
        dg += __shfl_xor(dg, off);
    }
    if (seg == 0) {
        betab[(size_t)m * NH + h] = sigm(db + bb[h]);
        gammab[(size_t)m * NH + h] = sigm(dg + bg[h]);
    }
}

// ------------------------------------------------------------- the scan
// grid: 256 blocks = (b,h) pairs x 4 column-groups; block: 320 thr = 1 producer
// wave + 4 consumer waves (16 cols x 16 thr/col, 4 rows each).
__global__ __launch_bounds__(320, 1) void k_scan(const __half* __restrict__ qb,
                                                 const __half* __restrict__ kb,
                                                 const __half* __restrict__ vb,
                                                 const __half* __restrict__ ab,
                                                 const __half* __restrict__ aRb,
                                                 const float* __restrict__ betab,
                                                 const float* __restrict__ gammab,
                                                 unsigned short* __restrict__ ob) {
    const int blk = blockIdx.x;
    const int bh = blk >> 2, cg = blk & 3;
    const int b = bh >> 4, h = bh & 15;

    const int KN = 0, KNA = 64, KNR = 128, AA = 192, AR = 256, QQ = 320, VV = 384, SC = 448;
    __shared__ __align__(16) float stg[2][512];

    const int t = threadIdx.x;

    // producer registers
    float pq = 0, pk = 0, pv = 0, pa = 0, paR = 0, pbeta = 0, pgamma = 0;
    size_t base = 0;
    if (t < 64) {
        base = ((size_t)b * T_SEQ) * DMODEL + h * 64 + t;
        pq = __half2float(qb[base]);
        pk = __half2float(kb[base]);
        pv = __half2float(vb[base]);
        pa = __half2float(ab[base]);
        paR = __half2float(aRb[base]);
        size_t bidx = ((size_t)b * T_SEQ) * NH + h;
        pbeta = betab[bidx];
        pgamma = gammab[bidx];
    }

    // consumer indices (unused by producer wave)
    const int ct = t - 64;
    const int col = ct >> 4, tr = ct & 15;
    const int ii = cg * 16 + col;
    const int j0 = tr * 4;
    float S0 = 0, S1 = 0, S2 = 0, S3 = 0, R0 = 0, R1 = 0, R2 = 0, R3 = 0;

    for (int st = 0; st < T_SEQ; st++) {
        const int buf = st & 1;
        if (t < 64) {
            float ss = pk * pk;
#pragma unroll
            for (int off = 32; off >= 1; off >>= 1) ss += __shfl_xor(ss, off);
            float inv = 1.f / fmaxf(sqrtf(ss), 1e-12f);
            float kn = pk * inv;
            stg[buf][KN + t] = kn;
            stg[buf][KNA + t] = kn * pa;
            stg[buf][KNR + t] = kn * paR;
            stg[buf][AA + t] = pa;
            stg[buf][AR + t] = paR;
            stg[buf][QQ + t] = pq;
            stg[buf][VV + t] = pv;
            if (t == 0) { stg[buf][SC] = pbeta; stg[buf][SC + 1] = pgamma; }
        }
        __syncthreads();
        if (t < 64) {
            if (st + 1 < T_SEQ) {  // prefetch next step (latency hidden by consumers)
                size_t idx = base + (size_t)(st + 1) * DMODEL;
                pq = __half2float(qb[idx]);
                pk = __half2float(kb[idx]);
                pv = __half2float(vb[idx]);
                pa = __half2float(ab[idx]);
                paR = __half2float(aRb[idx]);
                size_t bidx = ((size_t)(b * T_SEQ + st + 1)) * NH + h;
                pbeta = betab[bidx];
                pgamma = gammab[bidx];
            }
        } else {
            const float* sg = stg[buf];
            float4 kn4 = *(const float4*)&sg[KN + j0];
            float4 kna4 = *(const float4*)&sg[KNA + j0];
            float4 knr4 = *(const float4*)&sg[KNR + j0];
            float pred = S0 * kn4.x + S1 * kn4.y + S2 * kn4.z + S3 * kn4.w;
            float kp = S0 * kna4.x + S1 * kna4.y + S2 * kna4.z + S3 * kna4.w;
            float kpR = R0 * knr4.x + R1 * knr4.y + R2 * knr4.z + R3 * knr4.w;
#pragma unroll
            for (int off = 1; off < 16; off <<= 1) {
                pred += __shfl_xor(pred, off);
                kp += __shfl_xor(kp, off);
                kpR += __shfl_xor(kpR, off);
            }
            float v_i = sg[VV + ii];
            float beta = sg[SC], gamma = sg[SC + 1];
            float r = fminf(fmaxf(v_i - pred, -1.f), 1.f);
            float cS = beta * (v_i - kp);
            float cR = gamma * (r - kpR);
            float4 a4 = *(const float4*)&sg[AA + j0];
            float4 r4 = *(const float4*)&sg[AR + j0];
            float4 q4 = *(const float4*)&sg[QQ + j0];
            S0 = a4.x * S0 + cS * kn4.x;
            S1 = a4.y * S1 + cS * kn4.y;
            S2 = a4.z * S2 + cS * kn4.z;
            S3 = a4.w * S3 + cS * kn4.w;
            R0 = r4.x * R0 + cR * kn4.x;
            R1 = r4.y * R1 + cR * kn4.y;
            R2 = r4.z * R2 + cR * kn4.z;
            R3 = r4.w * R3 + cR * kn4.w;
            float o = (S0 + R0) * q4.x + (S1 + R1) * q4.y + (S2 + R2) * q4.z + (S3 + R3) * q4.w;
#pragma unroll
            for (int off = 1; off < 16; off <<= 1) o += __shfl_xor(o, off);
            if (tr == 0)
                ob[((size_t)(b * T_SEQ + st)) * DMODEL + h * 64 + ii] = f2bf(o);
        }
    }
}

// ---------------------------------------------------- output GEMM + residual
__global__ __launch_bounds__(256, 1) void k_out(const unsigned short* __restrict__ ob,
                                                const float* __restrict__ Wo,
                                                const float* __restrict__ x,
                                                float* __restrict__ out) {
    const int m0 = blockIdx.x * 128;
    const int n0 = blockIdx.y * 128;
    f32x4 acc[4][4];
    gemm128<1024>(ob, Wo, m0, n0, acc);
    const int lane = threadIdx.x & 63;
    const int wv = threadIdx.x >> 6;
    const int wm = wv >> 1, wn = wv & 1;
    const int ml = lane & 15, kq = lane >> 4;
#pragma unroll
    for (int mt = 0; mt < 4; mt++)
#pragma unroll
        for (int nt = 0; nt < 4; nt++) {
            const int rowg = m0 + wm * 64 + mt * 16 + kq * 4;
            const int colg = n0 + wn * 64 + nt * 16 + ml;
#pragma unroll
            for (int r = 0; r < 4; r++) {
                size_t idx = (size_t)(rowg + r) * DMODEL + colg;
                out[idx] = acc[mt][nt][r] + x[idx];
            }
        }
}

extern "C" void kernel_launch(void* const* d_in, const int* in_sizes, int n_in,
                              void* d_out, int out_size, void* d_ws, size_t ws_size,
                              hipStream_t stream) {
    const float* x = (const float*)d_in[0];
    const float* Wq = (const float*)d_in[1];
    const float* Wk = (const float*)d_in[2];
    const float* Wv = (const float*)d_in[3];
    const float* Wa = (const float*)d_in[4];
    const float* ba = (const float*)d_in[5];
    const float* Wb = (const float*)d_in[6];
    const float* bb = (const float*)d_in[7];
    const float* Wg = (const float*)d_in[8];
    const float* bg = (const float*)d_in[9];
    const float* WaR = (const float*)d_in[10];
    const float* baR = (const float*)d_in[11];
    const float* Wo = (const float*)d_in[12];
    const float* lnw = (const float*)d_in[13];
    const float* lnb = (const float*)d_in[14];

    const size_t SZ = 16777216ULL;  // 8192*1024*2 bytes (one fp16/bf16 plane)
    size_t need = 6 * SZ + 2 * 524288ULL;
    if (ws_size < need) return;

    char* ws = (char*)d_ws;
    __half* qb = (__half*)(ws + 0 * SZ);
    __half* kb = (__half*)(ws + 1 * SZ);
    __half* vb = (__half*)(ws + 2 * SZ);
    __half* ab = (__half*)(ws + 3 * SZ);
    __half* aRb = (__half*)(ws + 4 * SZ);
    unsigned short* xn = (unsigned short*)(ws + 5 * SZ);  // bf16; reused for o
    float* betab = (float*)(ws + 6 * SZ);
    float* gammab = (float*)(ws + 6 * SZ + 524288ULL);

    k_ln<<<dim3(MTOT), dim3(256), 0, stream>>>(x, lnw, lnb, xn);
    k_proj<<<dim3(64, 40), dim3(256), 0, stream>>>(xn, Wq, Wk, Wv, Wa, WaR, ba, baR,
                                                   qb, kb, vb, ab, aRb);
    k_bg<<<dim3(MTOT), dim3(256), 0, stream>>>(xn, Wb, bb, Wg, bg, betab, gammab);
    // scan writes o (bf16) over xn (xn dead after k_proj/k_bg)
    k_scan<<<dim3(256), dim3(320), 0, stream>>>(qb, kb, vb, ab, aRb, betab, gammab, xn);
    k_out<<<dim3(64, 8), dim3(256), 0, stream>>>(xn, Wo, x, (float*)d_out);
}

// Round 3
// 1234.681 us; speedup vs baseline: 1.5708x; 1.5708x over previous
//
#include <hip/hip_runtime.h>
#include <hip/hip_fp16.h>

#define B_SZ 4
#define T_SEQ 2048
#define NH 16
#define HD 64
#define DMODEL 1024
#define MTOT (B_SZ * T_SEQ)   // 8192

typedef __bf16 bf16x8 __attribute__((ext_vector_type(8)));
typedef float f32x4 __attribute__((ext_vector_type(4)));
typedef _Float16 f16x4 __attribute__((ext_vector_type(4)));

__device__ __forceinline__ unsigned short f2bf(float f) {
    union { float f; unsigned int i; } c; c.f = f;
    unsigned int u = c.i;
    u += 0x7fffu + ((u >> 16) & 1u);   // round-to-nearest-even
    return (unsigned short)(u >> 16);
}
__device__ __forceinline__ float sigm(float x) { return 1.f / (1.f + __expf(-x)); }

// DPP row_ror butterfly: after 4 stages every lane of a 16-lane row holds the row sum.
// VALU-pipe (v_mov_b32_dpp + v_add_f32), ~8 cyc/stage vs ~100 cyc for ds_swizzle.
template <int CTRL>
__device__ __forceinline__ float dppadd(float x) {
    int v = __builtin_amdgcn_update_dpp(0, __builtin_bit_cast(int, x), CTRL, 0xf, 0xf, false);
    return x + __builtin_bit_cast(float, v);
}
__device__ __forceinline__ float rowsum16(float x) {
    x = dppadd<0x128>(x);  // row_ror:8
    x = dppadd<0x124>(x);  // row_ror:4
    x = dppadd<0x122>(x);  // row_ror:2
    x = dppadd<0x121>(x);  // row_ror:1
    return x;
}

// ---------------------------------------------------------------- LayerNorm
__global__ __launch_bounds__(256, 1) void k_ln(const float* __restrict__ x,
                                               const float* __restrict__ lnw,
                                               const float* __restrict__ lnb,
                                               unsigned short* __restrict__ xn) {
    const int m = blockIdx.x;
    const int t = threadIdx.x;
    float4 xv = ((const float4*)(x + (size_t)m * DMODEL))[t];
    float s = xv.x + xv.y + xv.z + xv.w;
    float s2 = xv.x * xv.x + xv.y * xv.y + xv.z * xv.z + xv.w * xv.w;
#pragma unroll
    for (int off = 32; off >= 1; off >>= 1) {
        s += __shfl_xor(s, off);
        s2 += __shfl_xor(s2, off);
    }
    __shared__ float red[8];
    const int wid = t >> 6;
    if ((t & 63) == 0) { red[wid] = s; red[4 + wid] = s2; }
    __syncthreads();
    if (t == 0) {
        float su = red[0] + red[1] + red[2] + red[3];
        float sq = red[4] + red[5] + red[6] + red[7];
        float mu = su * (1.f / DMODEL);
        float var = sq * (1.f / DMODEL) - mu * mu;
        red[0] = mu;
        red[1] = rsqrtf(var + 1e-5f);
    }
    __syncthreads();
    float mu = red[0], rstd = red[1];
    float4 w4 = ((const float4*)lnw)[t];
    float4 b4 = ((const float4*)lnb)[t];
    ushort4 o;
    o.x = f2bf((xv.x - mu) * rstd * w4.x + b4.x);
    o.y = f2bf((xv.y - mu) * rstd * w4.y + b4.y);
    o.z = f2bf((xv.z - mu) * rstd * w4.z + b4.z);
    o.w = f2bf((xv.w - mu) * rstd * w4.w + b4.w);
    ((ushort4*)(xn + (size_t)m * DMODEL))[t] = o;
}

__device__ __forceinline__ void store_bf8(unsigned short* p, float4 a, float4 b) {
    ushort4 lo, hi;
    lo.x = f2bf(a.x); lo.y = f2bf(a.y); lo.z = f2bf(a.z); lo.w = f2bf(a.w);
    hi.x = f2bf(b.x); hi.y = f2bf(b.y); hi.z = f2bf(b.z); hi.w = f2bf(b.w);
    *(ushort4*)p = lo;
    *(ushort4*)(p + 4) = hi;
}

// ------------------------------------------------- 128x128 bf16 MFMA tile GEMM
template <int KDIM>
__device__ __forceinline__ void gemm128(const unsigned short* __restrict__ A,
                                        const float* __restrict__ Bw,
                                        int m0, int n0, f32x4 acc[4][4]) {
    __shared__ __align__(16) unsigned short sA[128 * 40];
    __shared__ __align__(16) unsigned short sB[128 * 40];

    const int t = threadIdx.x;
    const int lane = t & 63;
    const int wv = t >> 6;
    const int wm = wv >> 1, wn = wv & 1;
    const int ml = lane & 15, kq = lane >> 4;

#pragma unroll
    for (int i = 0; i < 4; i++)
#pragma unroll
        for (int j = 0; j < 4; j++) {
            f32x4 z; z[0] = 0.f; z[1] = 0.f; z[2] = 0.f; z[3] = 0.f;
            acc[i][j] = z;
        }

    const int r0 = t >> 2, q0 = t & 3;
    const int r1 = r0 + 64;
    const unsigned short* pA = A + (size_t)m0 * KDIM;
    const float* pB = Bw + (size_t)n0 * KDIM;

    uint4 ra0 = *(const uint4*)(pA + (size_t)r0 * KDIM + q0 * 8);
    uint4 ra1 = *(const uint4*)(pA + (size_t)r1 * KDIM + q0 * 8);
    float4 rb0a = *(const float4*)(pB + (size_t)r0 * KDIM + q0 * 8);
    float4 rb0b = *(const float4*)(pB + (size_t)r0 * KDIM + q0 * 8 + 4);
    float4 rb1a = *(const float4*)(pB + (size_t)r1 * KDIM + q0 * 8);
    float4 rb1b = *(const float4*)(pB + (size_t)r1 * KDIM + q0 * 8 + 4);

    for (int kb = 0; kb < KDIM / 32; kb++) {
        __syncthreads();
        *(uint4*)&sA[r0 * 40 + q0 * 8] = ra0;
        *(uint4*)&sA[r1 * 40 + q0 * 8] = ra1;
        store_bf8(&sB[r0 * 40 + q0 * 8], rb0a, rb0b);
        store_bf8(&sB[r1 * 40 + q0 * 8], rb1a, rb1b);
        __syncthreads();
        if (kb + 1 < KDIM / 32) {
            const unsigned short* nA = pA + (kb + 1) * 32;
            const float* nB = pB + (kb + 1) * 32;
            ra0 = *(const uint4*)(nA + (size_t)r0 * KDIM + q0 * 8);
            ra1 = *(const uint4*)(nA + (size_t)r1 * KDIM + q0 * 8);
            rb0a = *(const float4*)(nB + (size_t)r0 * KDIM + q0 * 8);
            rb0b = *(const float4*)(nB + (size_t)r0 * KDIM + q0 * 8 + 4);
            rb1a = *(const float4*)(nB + (size_t)r1 * KDIM + q0 * 8);
            rb1b = *(const float4*)(nB + (size_t)r1 * KDIM + q0 * 8 + 4);
        }
        bf16x8 af[4], bfr[4];
#pragma unroll
        for (int mt = 0; mt < 4; mt++)
            af[mt] = *(const bf16x8*)&sA[(wm * 64 + mt * 16 + ml) * 40 + kq * 8];
#pragma unroll
        for (int nt = 0; nt < 4; nt++)
            bfr[nt] = *(const bf16x8*)&sB[(wn * 64 + nt * 16 + ml) * 40 + kq * 8];
#pragma unroll
        for (int mt = 0; mt < 4; mt++)
#pragma unroll
            for (int nt = 0; nt < 4; nt++)
                acc[mt][nt] = __builtin_amdgcn_mfma_f32_16x16x32_bf16(af[mt], bfr[nt], acc[mt][nt], 0, 0, 0);
    }
}

// -------------------------------------------- fused 5-way projection GEMM
__global__ __launch_bounds__(256, 1) void k_proj(const unsigned short* __restrict__ xn,
                                                 const float* __restrict__ Wq,
                                                 const float* __restrict__ Wk,
                                                 const float* __restrict__ Wv,
                                                 const float* __restrict__ Wa,
                                                 const float* __restrict__ WaR,
                                                 const float* __restrict__ ba,
                                                 const float* __restrict__ baR,
                                                 __half* __restrict__ qo, __half* __restrict__ ko,
                                                 __half* __restrict__ vo, __half* __restrict__ ao,
                                                 __half* __restrict__ aRo) {
    const int m0 = blockIdx.x * 128;
    const int yt = blockIdx.y;
    const int widx = yt >> 3;
    const int n0 = (yt & 7) * 128;
    const float* W = widx == 0 ? Wq : widx == 1 ? Wk : widx == 2 ? Wv : widx == 3 ? Wa : WaR;
    f32x4 acc[4][4];
    gemm128<1024>(xn, W, m0, n0, acc);

    __half* outp = widx == 0 ? qo : widx == 1 ? ko : widx == 2 ? vo : widx == 3 ? ao : aRo;
    const float* bias = (widx == 3) ? ba : (widx == 4) ? baR : (const float*)0;
    const int lane = threadIdx.x & 63;
    const int wv = threadIdx.x >> 6;
    const int wm = wv >> 1, wn = wv & 1;
    const int ml = lane & 15, kq = lane >> 4;
#pragma unroll
    for (int mt = 0; mt < 4; mt++)
#pragma unroll
        for (int nt = 0; nt < 4; nt++) {
            const int rowg = m0 + wm * 64 + mt * 16 + kq * 4;
            const int colg = n0 + wn * 64 + nt * 16 + ml;
            float bval = bias ? bias[colg] : 0.f;
#pragma unroll
            for (int r = 0; r < 4; r++) {
                float v = acc[mt][nt][r];
                if (widx >= 3) v = sigm(v + bval);
                outp[(size_t)(rowg + r) * DMODEL + colg] = __float2half(v);
            }
        }
}

// --------------------------------------------------- beta/gamma skinny GEMM
__global__ __launch_bounds__(256, 1) void k_bg(const unsigned short* __restrict__ xn,
                                               const float* __restrict__ Wb,
                                               const float* __restrict__ bb,
                                               const float* __restrict__ Wg,
                                               const float* __restrict__ bg,
                                               float* __restrict__ betab,
                                               float* __restrict__ gammab) {
    const int m = blockIdx.x;
    const int t = threadIdx.x;
    const int h = t >> 4, seg = t & 15;
    const ushort4* xr = (const ushort4*)(xn + (size_t)m * DMODEL + seg * 64);
    const float4* wbr = (const float4*)(Wb + (size_t)h * DMODEL + seg * 64);
    const float4* wgr = (const float4*)(Wg + (size_t)h * DMODEL + seg * 64);
    float db = 0.f, dg = 0.f;
#pragma unroll
    for (int u = 0; u < 16; u++) {
        ushort4 a = xr[u];
        float4 w1 = wbr[u], w2 = wgr[u];
        union { unsigned int i; float f; } c0, c1, c2, c3;
        c0.i = ((unsigned int)a.x) << 16; c1.i = ((unsigned int)a.y) << 16;
        c2.i = ((unsigned int)a.z) << 16; c3.i = ((unsigned int)a.w) << 16;
        db += c0.f * w1.x + c1.f * w1.y + c2.f * w1.z + c3.f * w1.w;
        dg += c0.f * w2.x + c1.f * w2.y + c2.f * w2.z + c3.f * w2.w;
    }
#pragma unroll
    for (int off = 1; off < 16; off <<= 1) {
        db += __shfl_xor(db, off);
        dg += __shfl_xor(dg, off);
    }
    if (seg == 0) {
        betab[(size_t)m * NH + h] = sigm(db + bb[h]);
        gammab[(size_t)m * NH + h] = sigm(dg + bg[h]);
    }
}

// ------------------------------------------- k normalization (in-place, fp16)
// One 16-lane row-group per (bh,t) row; 4 elements per lane.
__global__ __launch_bounds__(256, 1) void k_prep(__half* __restrict__ kb) {
    const int row = blockIdx.x * 16 + (threadIdx.x >> 4);  // 0..131071
    const int tr = threadIdx.x & 15;
    const int bh = row >> 11, t = row & 2047;
    const size_t idx = ((size_t)((bh >> 4) * T_SEQ + t)) * DMODEL + (bh & 15) * 64 + tr * 4;
    f16x4 k4 = *(const f16x4*)((const __half*)kb + idx);
    float k0 = (float)k4[0], k1 = (float)k4[1], k2 = (float)k4[2], k3 = (float)k4[3];
    float ss = k0 * k0 + k1 * k1 + k2 * k2 + k3 * k3;
    ss = rowsum16(ss);
    float inv = 1.f / fmaxf(sqrtf(ss), 1e-12f);
    f16x4 o;
    o[0] = (_Float16)(k0 * inv); o[1] = (_Float16)(k1 * inv);
    o[2] = (_Float16)(k2 * inv); o[3] = (_Float16)(k3 * inv);
    *(f16x4*)(kb + idx) = o;
}

// ------------------------------------------------------------- the scan
// 256 blocks = 64 (b,h) x 4 column-groups; 256 thr = 16 columns x 16 lanes.
// No LDS, no barriers, no DS-pipe ops: DPP row reductions + reg-pipelined
// global loads (L2-resident streams).
__global__ __launch_bounds__(256, 1) void k_scan(const __half* __restrict__ qb,
                                                 const __half* __restrict__ knb,
                                                 const __half* __restrict__ vb,
                                                 const __half* __restrict__ ab,
                                                 const __half* __restrict__ aRb,
                                                 const float* __restrict__ betab,
                                                 const float* __restrict__ gammab,
                                                 unsigned short* __restrict__ ob) {
    const int blk = blockIdx.x;
    const int bh = blk >> 2, cg = blk & 3;
    const int b = bh >> 4, h = bh & 15;
    const int t = threadIdx.x;
    const int col = t >> 4, tr = t & 15;
    const int ii = cg * 16 + col;
    const int j0 = tr * 4;

    const size_t vecbase = ((size_t)b * T_SEQ) * DMODEL + h * 64 + j0;
    const size_t vbase = ((size_t)b * T_SEQ) * DMODEL + h * 64 + ii;
    const size_t bgbase = ((size_t)b * T_SEQ) * NH + h;

    const __half* pk = knb + vecbase;
    const __half* pq = qb + vecbase;
    const __half* pa = ab + vecbase;
    const __half* pr = aRb + vecbase;

    float S0 = 0, S1 = 0, S2 = 0, S3 = 0, R0 = 0, R1 = 0, R2 = 0, R3 = 0;

    // step-0 inputs
    f16x4 k4 = *(const f16x4*)pk;
    f16x4 q4 = *(const f16x4*)pq;
    f16x4 a4 = *(const f16x4*)pa;
    f16x4 r4 = *(const f16x4*)pr;
    float vc = (float)vb[vbase];
    float beta = betab[bgbase], gamma = gammab[bgbase];

    float kn0 = (float)k4[0], kn1 = (float)k4[1], kn2 = (float)k4[2], kn3 = (float)k4[3];
    float a0 = (float)a4[0], a1 = (float)a4[1], a2 = (float)a4[2], a3 = (float)a4[3];
    float aR0 = (float)r4[0], aR1 = (float)r4[1], aR2 = (float)r4[2], aR3 = (float)r4[3];
    float q0 = (float)q4[0], q1 = (float)q4[1], q2 = (float)q4[2], q3 = (float)q4[3];
    float kna0 = kn0 * a0, kna1 = kn1 * a1, kna2 = kn2 * a2, kna3 = kn3 * a3;
    float knr0 = kn0 * aR0, knr1 = kn1 * aR1, knr2 = kn2 * aR2, knr3 = kn3 * aR3;

    for (int st = 0; st < T_SEQ; st++) {
        // prefetch next step (wraps at the end; final prefetch unused)
        const int stn = (st + 1) & (T_SEQ - 1);
        const size_t voff = (size_t)stn * DMODEL;
        f16x4 nk = *(const f16x4*)(pk + voff);
        f16x4 nq = *(const f16x4*)(pq + voff);
        f16x4 na = *(const f16x4*)(pa + voff);
        f16x4 nr = *(const f16x4*)(pr + voff);
        float nvc = (float)vb[vbase + voff];
        float nbeta = betab[bgbase + (size_t)stn * NH];
        float ngamma = gammab[bgbase + (size_t)stn * NH];

        // ---- critical chain ----
        float pred = S0 * kn0 + S1 * kn1 + S2 * kn2 + S3 * kn3;
        float kp = S0 * kna0 + S1 * kna1 + S2 * kna2 + S3 * kna3;
        float kpR = R0 * knr0 + R1 * knr1 + R2 * knr2 + R3 * knr3;
        pred = rowsum16(pred);
        kp = rowsum16(kp);
        kpR = rowsum16(kpR);
        float rres = fminf(fmaxf(vc - pred, -1.f), 1.f);
        float cS = beta * (vc - kp);
        float cR = gamma * (rres - kpR);
        S0 = fmaf(a0, S0, cS * kn0);
        S1 = fmaf(a1, S1, cS * kn1);
        S2 = fmaf(a2, S2, cS * kn2);
        S3 = fmaf(a3, S3, cS * kn3);
        R0 = fmaf(aR0, R0, cR * kn0);
        R1 = fmaf(aR1, R1, cR * kn1);
        R2 = fmaf(aR2, R2, cR * kn2);
        R3 = fmaf(aR3, R3, cR * kn3);
        float o = (S0 + R0) * q0 + (S1 + R1) * q1 + (S2 + R2) * q2 + (S3 + R3) * q3;
        o = rowsum16(o);
        if (tr == 0)
            ob[vbase + (size_t)st * DMODEL] = f2bf(o);

        // ---- promote next -> cur (off critical chain) ----
        kn0 = (float)nk[0]; kn1 = (float)nk[1]; kn2 = (float)nk[2]; kn3 = (float)nk[3];
        a0 = (float)na[0]; a1 = (float)na[1]; a2 = (float)na[2]; a3 = (float)na[3];
        aR0 = (float)nr[0]; aR1 = (float)nr[1]; aR2 = (float)nr[2]; aR3 = (float)nr[3];
        q0 = (float)nq[0]; q1 = (float)nq[1]; q2 = (float)nq[2]; q3 = (float)nq[3];
        kna0 = kn0 * a0; kna1 = kn1 * a1; kna2 = kn2 * a2; kna3 = kn3 * a3;
        knr0 = kn0 * aR0; knr1 = kn1 * aR1; knr2 = kn2 * aR2; knr3 = kn3 * aR3;
        vc = nvc; beta = nbeta; gamma = ngamma;
    }
}

// ---------------------------------------------------- output GEMM + residual
__global__ __launch_bounds__(256, 1) void k_out(const unsigned short* __restrict__ ob,
                                                const float* __restrict__ Wo,
                                                const float* __restrict__ x,
                                                float* __restrict__ out) {
    const int m0 = blockIdx.x * 128;
    const int n0 = blockIdx.y * 128;
    f32x4 acc[4][4];
    gemm128<1024>(ob, Wo, m0, n0, acc);
    const int lane = threadIdx.x & 63;
    const int wv = threadIdx.x >> 6;
    const int wm = wv >> 1, wn = wv & 1;
    const int ml = lane & 15, kq = lane >> 4;
#pragma unroll
    for (int mt = 0; mt < 4; mt++)
#pragma unroll
        for (int nt = 0; nt < 4; nt++) {
            const int rowg = m0 + wm * 64 + mt * 16 + kq * 4;
            const int colg = n0 + wn * 64 + nt * 16 + ml;
#pragma unroll
            for (int r = 0; r < 4; r++) {
                size_t idx = (size_t)(rowg + r) * DMODEL + colg;
                out[idx] = acc[mt][nt][r] + x[idx];
            }
        }
}

extern "C" void kernel_launch(void* const* d_in, const int* in_sizes, int n_in,
                              void* d_out, int out_size, void* d_ws, size_t ws_size,
                              hipStream_t stream) {
    const float* x = (const float*)d_in[0];
    const float* Wq = (const float*)d_in[1];
    const float* Wk = (const float*)d_in[2];
    const float* Wv = (const float*)d_in[3];
    const float* Wa = (const float*)d_in[4];
    const float* ba = (const float*)d_in[5];
    const float* Wb = (const float*)d_in[6];
    const float* bb = (const float*)d_in[7];
    const float* Wg = (const float*)d_in[8];
    const float* bg = (const float*)d_in[9];
    const float* WaR = (const float*)d_in[10];
    const float* baR = (const float*)d_in[11];
    const float* Wo = (const float*)d_in[12];
    const float* lnw = (const float*)d_in[13];
    const float* lnb = (const float*)d_in[14];

    const size_t SZ = 16777216ULL;  // one fp16/bf16 plane (8192*1024*2 B)
    size_t need = 6 * SZ + 2 * 524288ULL;
    if (ws_size < need) return;

    char* ws = (char*)d_ws;
    __half* qb = (__half*)(ws + 0 * SZ);
    __half* kb = (__half*)(ws + 1 * SZ);
    __half* vb = (__half*)(ws + 2 * SZ);
    __half* ab = (__half*)(ws + 3 * SZ);
    __half* aRb = (__half*)(ws + 4 * SZ);
    unsigned short* xn = (unsigned short*)(ws + 5 * SZ);  // bf16; reused for o
    float* betab = (float*)(ws + 6 * SZ);
    float* gammab = (float*)(ws + 6 * SZ + 524288ULL);

    k_ln<<<dim3(MTOT), dim3(256), 0, stream>>>(x, lnw, lnb, xn);
    k_proj<<<dim3(64, 40), dim3(256), 0, stream>>>(xn, Wq, Wk, Wv, Wa, WaR, ba, baR,
                                                   qb, kb, vb, ab, aRb);
    k_bg<<<dim3(MTOT), dim3(256), 0, stream>>>(xn, Wb, bb, Wg, bg, betab, gammab);
    k_prep<<<dim3(MTOT * NH / 16), dim3(256), 0, stream>>>(kb);  // kb -> kn in place
    // scan writes o (bf16) over xn (xn dead after k_proj/k_bg)
    k_scan<<<dim3(256), dim3(256), 0, stream>>>(qb, kb, vb, ab, aRb, betab, gammab, xn);
    k_out<<<dim3(64, 8), dim3(256), 0, stream>>>(xn, Wo, x, (float*)d_out);
}

// Round 4
// 1051.193 us; speedup vs baseline: 1.8450x; 1.1746x over previous
//
#include <hip/hip_runtime.h>
#include <hip/hip_fp16.h>

#define B_SZ 4
#define T_SEQ 2048
#define NH 16
#define HD 64
#define DMODEL 1024
#define MTOT (B_SZ * T_SEQ)   // 8192

typedef __bf16 bf16x8 __attribute__((ext_vector_type(8)));
typedef float f32x4 __attribute__((ext_vector_type(4)));
typedef _Float16 f16x4 __attribute__((ext_vector_type(4)));

__device__ __forceinline__ unsigned short f2bf(float f) {
    union { float f; unsigned int i; } c; c.f = f;
    unsigned int u = c.i;
    u += 0x7fffu + ((u >> 16) & 1u);   // round-to-nearest-even
    return (unsigned short)(u >> 16);
}
__device__ __forceinline__ float sigm(float x) { return 1.f / (1.f + __expf(-x)); }

// DPP row_ror butterfly: after 4 stages every lane of a 16-lane row holds the row sum.
template <int CTRL>
__device__ __forceinline__ float dppadd(float x) {
    int v = __builtin_amdgcn_update_dpp(0, __builtin_bit_cast(int, x), CTRL, 0xf, 0xf, false);
    return x + __builtin_bit_cast(float, v);
}
__device__ __forceinline__ float rowsum16(float x) {
    x = dppadd<0x128>(x);  // row_ror:8
    x = dppadd<0x124>(x);  // row_ror:4
    x = dppadd<0x122>(x);  // row_ror:2
    x = dppadd<0x121>(x);  // row_ror:1
    return x;
}

// ---------------------------------------------------------------- LayerNorm
__global__ __launch_bounds__(256, 1) void k_ln(const float* __restrict__ x,
                                               const float* __restrict__ lnw,
                                               const float* __restrict__ lnb,
                                               unsigned short* __restrict__ xn) {
    const int m = blockIdx.x;
    const int t = threadIdx.x;
    float4 xv = ((const float4*)(x + (size_t)m * DMODEL))[t];
    float s = xv.x + xv.y + xv.z + xv.w;
    float s2 = xv.x * xv.x + xv.y * xv.y + xv.z * xv.z + xv.w * xv.w;
#pragma unroll
    for (int off = 32; off >= 1; off >>= 1) {
        s += __shfl_xor(s, off);
        s2 += __shfl_xor(s2, off);
    }
    __shared__ float red[8];
    const int wid = t >> 6;
    if ((t & 63) == 0) { red[wid] = s; red[4 + wid] = s2; }
    __syncthreads();
    if (t == 0) {
        float su = red[0] + red[1] + red[2] + red[3];
        float sq = red[4] + red[5] + red[6] + red[7];
        float mu = su * (1.f / DMODEL);
        float var = sq * (1.f / DMODEL) - mu * mu;
        red[0] = mu;
        red[1] = rsqrtf(var + 1e-5f);
    }
    __syncthreads();
    float mu = red[0], rstd = red[1];
    float4 w4 = ((const float4*)lnw)[t];
    float4 b4 = ((const float4*)lnb)[t];
    ushort4 o;
    o.x = f2bf((xv.x - mu) * rstd * w4.x + b4.x);
    o.y = f2bf((xv.y - mu) * rstd * w4.y + b4.y);
    o.z = f2bf((xv.z - mu) * rstd * w4.z + b4.z);
    o.w = f2bf((xv.w - mu) * rstd * w4.w + b4.w);
    ((ushort4*)(xn + (size_t)m * DMODEL))[t] = o;
}

__device__ __forceinline__ void store_bf8(unsigned short* p, float4 a, float4 b) {
    ushort4 lo, hi;
    lo.x = f2bf(a.x); lo.y = f2bf(a.y); lo.z = f2bf(a.z); lo.w = f2bf(a.w);
    hi.x = f2bf(b.x); hi.y = f2bf(b.y); hi.z = f2bf(b.z); hi.w = f2bf(b.w);
    *(ushort4*)p = lo;
    *(ushort4*)(p + 4) = hi;
}

// ------------------------------------------------- 128x128 bf16 MFMA tile GEMM
template <int KDIM>
__device__ __forceinline__ void gemm128(const unsigned short* __restrict__ A,
                                        const float* __restrict__ Bw,
                                        int m0, int n0, f32x4 acc[4][4]) {
    __shared__ __align__(16) unsigned short sA[128 * 40];
    __shared__ __align__(16) unsigned short sB[128 * 40];

    const int t = threadIdx.x;
    const int lane = t & 63;
    const int wv = t >> 6;
    const int wm = wv >> 1, wn = wv & 1;
    const int ml = lane & 15, kq = lane >> 4;

#pragma unroll
    for (int i = 0; i < 4; i++)
#pragma unroll
        for (int j = 0; j < 4; j++) {
            f32x4 z; z[0] = 0.f; z[1] = 0.f; z[2] = 0.f; z[3] = 0.f;
            acc[i][j] = z;
        }

    const int r0 = t >> 2, q0 = t & 3;
    const int r1 = r0 + 64;
    const unsigned short* pA = A + (size_t)m0 * KDIM;
    const float* pB = Bw + (size_t)n0 * KDIM;

    uint4 ra0 = *(const uint4*)(pA + (size_t)r0 * KDIM + q0 * 8);
    uint4 ra1 = *(const uint4*)(pA + (size_t)r1 * KDIM + q0 * 8);
    float4 rb0a = *(const float4*)(pB + (size_t)r0 * KDIM + q0 * 8);
    float4 rb0b = *(const float4*)(pB + (size_t)r0 * KDIM + q0 * 8 + 4);
    float4 rb1a = *(const float4*)(pB + (size_t)r1 * KDIM + q0 * 8);
    float4 rb1b = *(const float4*)(pB + (size_t)r1 * KDIM + q0 * 8 + 4);

    for (int kb = 0; kb < KDIM / 32; kb++) {
        __syncthreads();
        *(uint4*)&sA[r0 * 40 + q0 * 8] = ra0;
        *(uint4*)&sA[r1 * 40 + q0 * 8] = ra1;
        store_bf8(&sB[r0 * 40 + q0 * 8], rb0a, rb0b);
        store_bf8(&sB[r1 * 40 + q0 * 8], rb1a, rb1b);
        __syncthreads();
        if (kb + 1 < KDIM / 32) {
            const unsigned short* nA = pA + (kb + 1) * 32;
            const float* nB = pB + (kb + 1) * 32;
            ra0 = *(const uint4*)(nA + (size_t)r0 * KDIM + q0 * 8);
            ra1 = *(const uint4*)(nA + (size_t)r1 * KDIM + q0 * 8);
            rb0a = *(const float4*)(nB + (size_t)r0 * KDIM + q0 * 8);
            rb0b = *(const float4*)(nB + (size_t)r0 * KDIM + q0 * 8 + 4);
            rb1a = *(const float4*)(nB + (size_t)r1 * KDIM + q0 * 8);
            rb1b = *(const float4*)(nB + (size_t)r1 * KDIM + q0 * 8 + 4);
        }
        bf16x8 af[4], bfr[4];
#pragma unroll
        for (int mt = 0; mt < 4; mt++)
            af[mt] = *(const bf16x8*)&sA[(wm * 64 + mt * 16 + ml) * 40 + kq * 8];
#pragma unroll
        for (int nt = 0; nt < 4; nt++)
            bfr[nt] = *(const bf16x8*)&sB[(wn * 64 + nt * 16 + ml) * 40 + kq * 8];
#pragma unroll
        for (int mt = 0; mt < 4; mt++)
#pragma unroll
            for (int nt = 0; nt < 4; nt++)
                acc[mt][nt] = __builtin_amdgcn_mfma_f32_16x16x32_bf16(af[mt], bfr[nt], acc[mt][nt], 0, 0, 0);
    }
}

// -------------------------------------------- fused 5-way projection GEMM
__global__ __launch_bounds__(256, 1) void k_proj(const unsigned short* __restrict__ xn,
                                                 const float* __restrict__ Wq,
                                                 const float* __restrict__ Wk,
                                                 const float* __restrict__ Wv,
                                                 const float* __restrict__ Wa,
                                                 const float* __restrict__ WaR,
                                                 const float* __restrict__ ba,
                                                 const float* __restrict__ baR,
                                                 __half* __restrict__ qo, __half* __restrict__ ko,
                                                 __half* __restrict__ vo, __half* __restrict__ ao,
                                                 __half* __restrict__ aRo) {
    const int m0 = blockIdx.x * 128;
    const int yt = blockIdx.y;
    const int widx = yt >> 3;
    const int n0 = (yt & 7) * 128;
    const float* W = widx == 0 ? Wq : widx == 1 ? Wk : widx == 2 ? Wv : widx == 3 ? Wa : WaR;
    f32x4 acc[4][4];
    gemm128<1024>(xn, W, m0, n0, acc);

    __half* outp = widx == 0 ? qo : widx == 1 ? ko : widx == 2 ? vo : widx == 3 ? ao : aRo;
    const float* bias = (widx == 3) ? ba : (widx == 4) ? baR : (const float*)0;
    const int lane = threadIdx.x & 63;
    const int wv = threadIdx.x >> 6;
    const int wm = wv >> 1, wn = wv & 1;
    const int ml = lane & 15, kq = lane >> 4;
#pragma unroll
    for (int mt = 0; mt < 4; mt++)
#pragma unroll
        for (int nt = 0; nt < 4; nt++) {
            const int rowg = m0 + wm * 64 + mt * 16 + kq * 4;
            const int colg = n0 + wn * 64 + nt * 16 + ml;
            float bval = bias ? bias[colg] : 0.f;
#pragma unroll
            for (int r = 0; r < 4; r++) {
                float v = acc[mt][nt][r];
                if (widx >= 3) v = sigm(v + bval);
                outp[(size_t)(rowg + r) * DMODEL + colg] = __float2half(v);
            }
        }
}

// --------------------------------------------------- beta/gamma skinny GEMM
__global__ __launch_bounds__(256, 1) void k_bg(const unsigned short* __restrict__ xn,
                                               const float* __restrict__ Wb,
                                               const float* __restrict__ bb,
                                               const float* __restrict__ Wg,
                                               const float* __restrict__ bg,
                                               float* __restrict__ betab,
                                               float* __restrict__ gammab) {
    const int m = blockIdx.x;
    const int t = threadIdx.x;
    const int h = t >> 4, seg = t & 15;
    const ushort4* xr = (const ushort4*)(xn + (size_t)m * DMODEL + seg * 64);
    const float4* wbr = (const float4*)(Wb + (size_t)h * DMODEL + seg * 64);
    const float4* wgr = (const float4*)(Wg + (size_t)h * DMODEL + seg * 64);
    float db = 0.f, dg = 0.f;
#pragma unroll
    for (int u = 0; u < 16; u++) {
        ushort4 a = xr[u];
        float4 w1 = wbr[u], w2 = wgr[u];
        union { unsigned int i; float f; } c0, c1, c2, c3;
        c0.i = ((unsigned int)a.x) << 16; c1.i = ((unsigned int)a.y) << 16;
        c2.i = ((unsigned int)a.z) << 16; c3.i = ((unsigned int)a.w) << 16;
        db += c0.f * w1.x + c1.f * w1.y + c2.f * w1.z + c3.f * w1.w;
        dg += c0.f * w2.x + c1.f * w2.y + c2.f * w2.z + c3.f * w2.w;
    }
#pragma unroll
    for (int off = 1; off < 16; off <<= 1) {
        db += __shfl_xor(db, off);
        dg += __shfl_xor(dg, off);
    }
    if (seg == 0) {
        betab[(size_t)m * NH + h] = sigm(db + bb[h]);
        gammab[(size_t)m * NH + h] = sigm(dg + bg[h]);
    }
}

// ------------------------------------------- k normalization (in-place, fp16)
__global__ __launch_bounds__(256, 1) void k_prep(__half* __restrict__ kb) {
    const int row = blockIdx.x * 16 + (threadIdx.x >> 4);
    const int tr = threadIdx.x & 15;
    const int bh = row >> 11, t = row & 2047;
    const size_t idx = ((size_t)((bh >> 4) * T_SEQ + t)) * DMODEL + (bh & 15) * 64 + tr * 4;
    f16x4 k4 = *(const f16x4*)((const __half*)kb + idx);
    float k0 = (float)k4[0], k1 = (float)k4[1], k2 = (float)k4[2], k3 = (float)k4[3];
    float ss = k0 * k0 + k1 * k1 + k2 * k2 + k3 * k3;
    ss = rowsum16(ss);
    float inv = 1.f / fmaxf(sqrtf(ss), 1e-12f);
    f16x4 o;
    o[0] = (_Float16)(k0 * inv); o[1] = (_Float16)(k1 * inv);
    o[2] = (_Float16)(k2 * inv); o[3] = (_Float16)(k3 * inv);
    *(f16x4*)(kb + idx) = o;
}

// ------------------------------------------------------------- the scan
// 256 blocks = 64 (b,h) x 4 column-groups; 256 thr = 16 columns x 16 lanes.
// 3-slot register rotation: loads prefetch distance 3, cvts distance 1,
// so load->use gap ~2 full steps (>500 cyc) hides L2/L3 latency.
__global__ __launch_bounds__(256, 1) void k_scan(const __half* __restrict__ qb,
                                                 const __half* __restrict__ knb,
                                                 const __half* __restrict__ vb,
                                                 const __half* __restrict__ ab,
                                                 const __half* __restrict__ aRb,
                                                 const float* __restrict__ betab,
                                                 const float* __restrict__ gammab,
                                                 unsigned short* __restrict__ ob) {
    const int blk = blockIdx.x;
    const int bh = blk >> 2, cg = blk & 3;
    const int b = bh >> 4, h = bh & 15;
    const int t = threadIdx.x;
    const int col = t >> 4, tr = t & 15;
    const int ii = cg * 16 + col;
    const int j0 = tr * 4;

    const size_t vecbase = ((size_t)b * T_SEQ) * DMODEL + h * 64 + j0;
    const size_t vbase = ((size_t)b * T_SEQ) * DMODEL + h * 64 + ii;
    const size_t bgbase = ((size_t)b * T_SEQ) * NH + h;

    const __half* pk = knb + vecbase;
    const __half* pq = qb + vecbase;
    const __half* pa = ab + vecbase;
    const __half* pr = aRb + vecbase;

    float S0 = 0, S1 = 0, S2 = 0, S3 = 0, R0 = 0, R1 = 0, R2 = 0, R3 = 0;

    f16x4 rk[3], rq[3], ra[3], rr[3];
    __half rv[3];
    float rbe[3], rga[3];
    f32x4 fkn[3], fq[3], fa[3], fr[3];
    float fv[3];

#pragma unroll
    for (int p = 0; p < 3; p++) {
        const size_t voff = (size_t)p * DMODEL;
        rk[p] = *(const f16x4*)(pk + voff);
        rq[p] = *(const f16x4*)(pq + voff);
        ra[p] = *(const f16x4*)(pa + voff);
        rr[p] = *(const f16x4*)(pr + voff);
        rv[p] = vb[vbase + voff];
        rbe[p] = betab[bgbase + (size_t)p * NH];
        rga[p] = gammab[bgbase + (size_t)p * NH];
    }
    // cvt slot 0 (step 0)
    fkn[0][0] = (float)rk[0][0]; fkn[0][1] = (float)rk[0][1]; fkn[0][2] = (float)rk[0][2]; fkn[0][3] = (float)rk[0][3];
    fq[0][0] = (float)rq[0][0]; fq[0][1] = (float)rq[0][1]; fq[0][2] = (float)rq[0][2]; fq[0][3] = (float)rq[0][3];
    fa[0][0] = (float)ra[0][0]; fa[0][1] = (float)ra[0][1]; fa[0][2] = (float)ra[0][2]; fa[0][3] = (float)ra[0][3];
    fr[0][0] = (float)rr[0][0]; fr[0][1] = (float)rr[0][1]; fr[0][2] = (float)rr[0][2]; fr[0][3] = (float)rr[0][3];
    fv[0] = (float)rv[0];

#define SCAN_BODY(P, PN)                                                              \
    {                                                                                 \
        const int s = st + (P);                                                       \
        const float beta = rbe[P], gamma = rga[P];                                    \
        /* prefetch step s+3 into slot P (its raw was cvt'd last body) */             \
        {                                                                             \
            const size_t voff = (size_t)((s + 3) & (T_SEQ - 1)) * DMODEL;             \
            rk[P] = *(const f16x4*)(pk + voff);                                       \
            rq[P] = *(const f16x4*)(pq + voff);                                       \
            ra[P] = *(const f16x4*)(pa + voff);                                       \
            rr[P] = *(const f16x4*)(pr + voff);                                       \
            rv[P] = vb[vbase + voff];                                                 \
            const size_t soff = (size_t)((s + 3) & (T_SEQ - 1)) * NH;                 \
            rbe[P] = betab[bgbase + soff];                                            \
            rga[P] = gammab[bgbase + soff];                                           \
        }                                                                             \
        /* cvt slot PN = step s+1 (loaded 2 bodies ago) */                            \
        fkn[PN][0] = (float)rk[PN][0]; fkn[PN][1] = (float)rk[PN][1];                 \
        fkn[PN][2] = (float)rk[PN][2]; fkn[PN][3] = (float)rk[PN][3];                 \
        fq[PN][0] = (float)rq[PN][0]; fq[PN][1] = (float)rq[PN][1];                   \
        fq[PN][2] = (float)rq[PN][2]; fq[PN][3] = (float)rq[PN][3];                   \
        fa[PN][0] = (float)ra[PN][0]; fa[PN][1] = (float)ra[PN][1];                   \
        fa[PN][2] = (float)ra[PN][2]; fa[PN][3] = (float)ra[PN][3];                   \
        fr[PN][0] = (float)rr[PN][0]; fr[PN][1] = (float)rr[PN][1];                   \
        fr[PN][2] = (float)rr[PN][2]; fr[PN][3] = (float)rr[PN][3];                   \
        fv[PN] = (float)rv[PN];                                                       \
        /* critical chain for step s, float set P */                                  \
        {                                                                             \
            const float kn0 = fkn[P][0], kn1 = fkn[P][1], kn2 = fkn[P][2], kn3 = fkn[P][3]; \
            const float a0 = fa[P][0], a1 = fa[P][1], a2 = fa[P][2], a3 = fa[P][3];   \
            const float x0 = fr[P][0], x1 = fr[P][1], x2 = fr[P][2], x3 = fr[P][3];   \
            const float vc = fv[P];                                                   \
            float pred = S0 * kn0 + S1 * kn1 + S2 * kn2 + S3 * kn3;                   \
            float Sd0 = a0 * S0, Sd1 = a1 * S1, Sd2 = a2 * S2, Sd3 = a3 * S3;         \
            float Rd0 = x0 * R0, Rd1 = x1 * R1, Rd2 = x2 * R2, Rd3 = x3 * R3;         \
            float kp = Sd0 * kn0 + Sd1 * kn1 + Sd2 * kn2 + Sd3 * kn3;                 \
            float kpR = Rd0 * kn0 + Rd1 * kn1 + Rd2 * kn2 + Rd3 * kn3;                \
            pred = rowsum16(pred);                                                    \
            kp = rowsum16(kp);                                                        \
            kpR = rowsum16(kpR);                                                      \
            const float rres = fminf(fmaxf(vc - pred, -1.f), 1.f);                    \
            const float cS = beta * (vc - kp);                                        \
            const float cR = gamma * (rres - kpR);                                    \
            S0 = fmaf(cS, kn0, Sd0); S1 = fmaf(cS, kn1, Sd1);                         \
            S2 = fmaf(cS, kn2, Sd2); S3 = fmaf(cS, kn3, Sd3);                         \
            R0 = fmaf(cR, kn0, Rd0); R1 = fmaf(cR, kn1, Rd1);                         \
            R2 = fmaf(cR, kn2, Rd2); R3 = fmaf(cR, kn3, Rd3);                         \
            float o = (S0 + R0) * fq[P][0] + (S1 + R1) * fq[P][1] +                   \
                      (S2 + R2) * fq[P][2] + (S3 + R3) * fq[P][3];                    \
            o = rowsum16(o);                                                          \
            if (tr == 0 && s < T_SEQ)                                                 \
                ob[vbase + (size_t)s * DMODEL] = f2bf(o);                             \
        }                                                                             \
    }

    for (int st = 0; st < T_SEQ; st += 3) {
        SCAN_BODY(0, 1)
        SCAN_BODY(1, 2)
        SCAN_BODY(2, 0)
    }
#undef SCAN_BODY
}

// ---------------------------------------------------- output GEMM + residual
__global__ __launch_bounds__(256, 1) void k_out(const unsigned short* __restrict__ ob,
                                                const float* __restrict__ Wo,
                                                const float* __restrict__ x,
                                                float* __restrict__ out) {
    const int m0 = blockIdx.x * 128;
    const int n0 = blockIdx.y * 128;
    f32x4 acc[4][4];
    gemm128<1024>(ob, Wo, m0, n0, acc);
    const int lane = threadIdx.x & 63;
    const int wv = threadIdx.x >> 6;
    const int wm = wv >> 1, wn = wv & 1;
    const int ml = lane & 15, kq = lane >> 4;
#pragma unroll
    for (int mt = 0; mt < 4; mt++)
#pragma unroll
        for (int nt = 0; nt < 4; nt++) {
            const int rowg = m0 + wm * 64 + mt * 16 + kq * 4;
            const int colg = n0 + wn * 64 + nt * 16 + ml;
#pragma unroll
            for (int r = 0; r < 4; r++) {
                size_t idx = (size_t)(rowg + r) * DMODEL + colg;
                out[idx] = acc[mt][nt][r] + x[idx];
            }
        }
}

extern "C" void kernel_launch(void* const* d_in, const int* in_sizes, int n_in,
                              void* d_out, int out_size, void* d_ws, size_t ws_size,
                              hipStream_t stream) {
    const float* x = (const float*)d_in[0];
    const float* Wq = (const float*)d_in[1];
    const float* Wk = (const float*)d_in[2];
    const float* Wv = (const float*)d_in[3];
    const float* Wa = (const float*)d_in[4];
    const float* ba = (const float*)d_in[5];
    const float* Wb = (const float*)d_in[6];
    const float* bb = (const float*)d_in[7];
    const float* Wg = (const float*)d_in[8];
    const float* bg = (const float*)d_in[9];
    const float* WaR = (const float*)d_in[10];
    const float* baR = (const float*)d_in[11];
    const float* Wo = (const float*)d_in[12];
    const float* lnw = (const float*)d_in[13];
    const float* lnb = (const float*)d_in[14];

    const size_t SZ = 16777216ULL;  // one fp16/bf16 plane (8192*1024*2 B)
    size_t need = 6 * SZ + 2 * 524288ULL;
    if (ws_size < need) return;

    char* ws = (char*)d_ws;
    __half* qb = (__half*)(ws + 0 * SZ);
    __half* kb = (__half*)(ws + 1 * SZ);
    __half* vb = (__half*)(ws + 2 * SZ);
    __half* ab = (__half*)(ws + 3 * SZ);
    __half* aRb = (__half*)(ws + 4 * SZ);
    unsigned short* xn = (unsigned short*)(ws + 5 * SZ);  // bf16; reused for o
    float* betab = (float*)(ws + 6 * SZ);
    float* gammab = (float*)(ws + 6 * SZ + 524288ULL);

    k_ln<<<dim3(MTOT), dim3(256), 0, stream>>>(x, lnw, lnb, xn);
    k_proj<<<dim3(64, 40), dim3(256), 0, stream>>>(xn, Wq, Wk, Wv, Wa, WaR, ba, baR,
                                                   qb, kb, vb, ab, aRb);
    k_bg<<<dim3(MTOT), dim3(256), 0, stream>>>(xn, Wb, bb, Wg, bg, betab, gammab);
    k_prep<<<dim3(MTOT * NH / 16), dim3(256), 0, stream>>>(kb);  // kb -> kn in place
    // scan writes o (bf16) over xn (xn dead after k_proj/k_bg)
    k_scan<<<dim3(256), dim3(256), 0, stream>>>(qb, kb, vb, ab, aRb, betab, gammab, xn);
    k_out<<<dim3(64, 8), dim3(256), 0, stream>>>(xn, Wo, x, (float*)d_out);
}

// Round 5
// 999.256 us; speedup vs baseline: 1.9409x; 1.0520x over previous
//
#include <hip/hip_runtime.h>
#include <hip/hip_fp16.h>

#define B_SZ 4
#define T_SEQ 2048
#define NH 16
#define HD 64
#define DMODEL 1024
#define MTOT (B_SZ * T_SEQ)   // 8192

typedef __bf16 bf16x8 __attribute__((ext_vector_type(8)));
typedef float f32x4 __attribute__((ext_vector_type(4)));
typedef _Float16 f16x4 __attribute__((ext_vector_type(4)));

__device__ __forceinline__ unsigned short f2bf(float f) {
    union { float f; unsigned int i; } c; c.f = f;
    unsigned int u = c.i;
    u += 0x7fffu + ((u >> 16) & 1u);   // round-to-nearest-even
    return (unsigned short)(u >> 16);
}
__device__ __forceinline__ float sigm(float x) { return 1.f / (1.f + __expf(-x)); }

// async global->LDS, 16B per lane; LDS dest = wave-uniform base + lane*16
__device__ __forceinline__ void gload_lds16(const unsigned short* g, unsigned short* l) {
    __builtin_amdgcn_global_load_lds(
        (const __attribute__((address_space(1))) void*)g,
        (__attribute__((address_space(3))) void*)l, 16, 0, 0);
}

// DPP row_ror butterfly: after 4 stages every lane of a 16-lane row holds the row sum.
template <int CTRL>
__device__ __forceinline__ float dppadd(float x) {
    int v = __builtin_amdgcn_update_dpp(0, __builtin_bit_cast(int, x), CTRL, 0xf, 0xf, false);
    return x + __builtin_bit_cast(float, v);
}
__device__ __forceinline__ float rowsum16(float x) {
    x = dppadd<0x128>(x);  // row_ror:8
    x = dppadd<0x124>(x);  // row_ror:4
    x = dppadd<0x122>(x);  // row_ror:2
    x = dppadd<0x121>(x);  // row_ror:1
    return x;
}

// ---------------------------------------------------------------- LayerNorm
__global__ __launch_bounds__(256, 1) void k_ln(const float* __restrict__ x,
                                               const float* __restrict__ lnw,
                                               const float* __restrict__ lnb,
                                               unsigned short* __restrict__ xn) {
    const int m = blockIdx.x;
    const int t = threadIdx.x;
    float4 xv = ((const float4*)(x + (size_t)m * DMODEL))[t];
    float s = xv.x + xv.y + xv.z + xv.w;
    float s2 = xv.x * xv.x + xv.y * xv.y + xv.z * xv.z + xv.w * xv.w;
#pragma unroll
    for (int off = 32; off >= 1; off >>= 1) {
        s += __shfl_xor(s, off);
        s2 += __shfl_xor(s2, off);
    }
    __shared__ float red[8];
    const int wid = t >> 6;
    if ((t & 63) == 0) { red[wid] = s; red[4 + wid] = s2; }
    __syncthreads();
    if (t == 0) {
        float su = red[0] + red[1] + red[2] + red[3];
        float sq = red[4] + red[5] + red[6] + red[7];
        float mu = su * (1.f / DMODEL);
        float var = sq * (1.f / DMODEL) - mu * mu;
        red[0] = mu;
        red[1] = rsqrtf(var + 1e-5f);
    }
    __syncthreads();
    float mu = red[0], rstd = red[1];
    float4 w4 = ((const float4*)lnw)[t];
    float4 b4 = ((const float4*)lnb)[t];
    ushort4 o;
    o.x = f2bf((xv.x - mu) * rstd * w4.x + b4.x);
    o.y = f2bf((xv.y - mu) * rstd * w4.y + b4.y);
    o.z = f2bf((xv.z - mu) * rstd * w4.z + b4.z);
    o.w = f2bf((xv.w - mu) * rstd * w4.w + b4.w);
    ((ushort4*)(xn + (size_t)m * DMODEL))[t] = o;
}

// ------------------------------------------- fp32 -> bf16 weight conversion
struct WPtrs { const float* p0; const float* p1; const float* p2; const float* p3; const float* p4; };

__global__ __launch_bounds__(256, 1) void k_wconv(WPtrs w, unsigned short* __restrict__ dst) {
    const int plane = blockIdx.y;
    const float* src = plane == 0 ? w.p0 : plane == 1 ? w.p1 : plane == 2 ? w.p2
                                                             : plane == 3 ? w.p3 : w.p4;
    const size_t i = ((size_t)blockIdx.x * 256 + threadIdx.x) * 8;
    float4 f0 = *(const float4*)(src + i);
    float4 f1 = *(const float4*)(src + i + 4);
    uint4 o;
    o.x = (unsigned)f2bf(f0.x) | ((unsigned)f2bf(f0.y) << 16);
    o.y = (unsigned)f2bf(f0.z) | ((unsigned)f2bf(f0.w) << 16);
    o.z = (unsigned)f2bf(f1.x) | ((unsigned)f2bf(f1.y) << 16);
    o.w = (unsigned)f2bf(f1.z) | ((unsigned)f2bf(f1.w) << 16);
    *(uint4*)(dst + (size_t)plane * 1048576 + i) = o;
}

__global__ __launch_bounds__(256, 1) void k_cvt1(const float* __restrict__ src,
                                                 unsigned short* __restrict__ dst) {
    const size_t i = ((size_t)blockIdx.x * 256 + threadIdx.x) * 8;
    float4 f0 = *(const float4*)(src + i);
    float4 f1 = *(const float4*)(src + i + 4);
    uint4 o;
    o.x = (unsigned)f2bf(f0.x) | ((unsigned)f2bf(f0.y) << 16);
    o.y = (unsigned)f2bf(f0.z) | ((unsigned)f2bf(f0.w) << 16);
    o.z = (unsigned)f2bf(f1.x) | ((unsigned)f2bf(f1.y) << 16);
    o.w = (unsigned)f2bf(f1.z) | ((unsigned)f2bf(f1.w) << 16);
    *(uint4*)(dst + i) = o;
}

// ------------------------------------------------- 128x128 bf16 MFMA tile GEMM
// m97 structure: global_load_lds width-16 staging, 128x32 bf16 tiles (lane-order
// LDS, no pad), 2-barrier K-loop, 16 MFMA per K-block.
template <int KDIM>
__device__ __forceinline__ void gemm128(const unsigned short* __restrict__ A,
                                        const unsigned short* __restrict__ Bw,
                                        int m0, int n0, f32x4 acc[4][4]) {
    __shared__ __align__(16) unsigned short sA[128 * 32];
    __shared__ __align__(16) unsigned short sB[128 * 32];

    const int t = threadIdx.x;
    const int lane = t & 63;
    const int wv = t >> 6;
    const int wm = wv >> 1, wn = wv & 1;
    const int ml = lane & 15, kq = lane >> 4;

#pragma unroll
    for (int i = 0; i < 4; i++)
#pragma unroll
        for (int j = 0; j < 4; j++) {
            f32x4 z; z[0] = 0.f; z[1] = 0.f; z[2] = 0.f; z[3] = 0.f;
            acc[i][j] = z;
        }

    // staging: chunk c = t (call0) / t+256 (call1); row = c>>2, col8 = (c&3)*8
    const unsigned short* pA = A + (size_t)m0 * KDIM;
    const unsigned short* pB = Bw + (size_t)n0 * KDIM;
    const unsigned short* gA0 = pA + (size_t)(t >> 2) * KDIM + (t & 3) * 8;
    const unsigned short* gA1 = gA0 + (size_t)64 * KDIM;
    const unsigned short* gB0 = pB + (size_t)(t >> 2) * KDIM + (t & 3) * 8;
    const unsigned short* gB1 = gB0 + (size_t)64 * KDIM;
    unsigned short* lA0 = sA + wv * 512;   // bytes: wv*1024; +lane*16 done by HW
    unsigned short* lA1 = lA0 + 2048;      // +4096 B
    unsigned short* lB0 = sB + wv * 512;
    unsigned short* lB1 = lB0 + 2048;

    for (int kb = 0; kb < KDIM / 32; kb++) {
        const int ko = kb * 32;
        gload_lds16(gA0 + ko, lA0);
        gload_lds16(gA1 + ko, lA1);
        gload_lds16(gB0 + ko, lB0);
        gload_lds16(gB1 + ko, lB1);
        __syncthreads();
        bf16x8 af[4], bfr[4];
#pragma unroll
        for (int mt = 0; mt < 4; mt++)
            af[mt] = *(const bf16x8*)&sA[(wm * 64 + mt * 16 + ml) * 32 + kq * 8];
#pragma unroll
        for (int nt = 0; nt < 4; nt++)
            bfr[nt] = *(const bf16x8*)&sB[(wn * 64 + nt * 16 + ml) * 32 + kq * 8];
#pragma unroll
        for (int mt = 0; mt < 4; mt++)
#pragma unroll
            for (int nt = 0; nt < 4; nt++)
                acc[mt][nt] = __builtin_amdgcn_mfma_f32_16x16x32_bf16(af[mt], bfr[nt], acc[mt][nt], 0, 0, 0);
        __syncthreads();
    }
}

// -------------------------------------------- fused 5-way projection GEMM
__global__ __launch_bounds__(256, 1) void k_proj(const unsigned short* __restrict__ xn,
                                                 const unsigned short* __restrict__ wbf,
                                                 const float* __restrict__ ba,
                                                 const float* __restrict__ baR,
                                                 __half* __restrict__ qo, __half* __restrict__ ko,
                                                 __half* __restrict__ vo, __half* __restrict__ ao,
                                                 __half* __restrict__ aRo) {
    const int m0 = blockIdx.x * 128;
    const int yt = blockIdx.y;
    const int widx = yt >> 3;
    const int n0 = (yt & 7) * 128;
    const unsigned short* W = wbf + (size_t)widx * 1048576;
    f32x4 acc[4][4];
    gemm128<1024>(xn, W, m0, n0, acc);

    __half* outp = widx == 0 ? qo : widx == 1 ? ko : widx == 2 ? vo : widx == 3 ? ao : aRo;
    const float* bias = (widx == 3) ? ba : (widx == 4) ? baR : (const float*)0;
    const int lane = threadIdx.x & 63;
    const int wv = threadIdx.x >> 6;
    const int wm = wv >> 1, wn = wv & 1;
    const int ml = lane & 15, kq = lane >> 4;
#pragma unroll
    for (int mt = 0; mt < 4; mt++)
#pragma unroll
        for (int nt = 0; nt < 4; nt++) {
            const int rowg = m0 + wm * 64 + mt * 16 + kq * 4;
            const int colg = n0 + wn * 64 + nt * 16 + ml;
            float bval = bias ? bias[colg] : 0.f;
#pragma unroll
            for (int r = 0; r < 4; r++) {
                float v = acc[mt][nt][r];
                if (widx >= 3) v = sigm(v + bval);
                outp[(size_t)(rowg + r) * DMODEL + colg] = __float2half(v);
            }
        }
}

// --------------------------------------------------- beta/gamma skinny GEMM
__global__ __launch_bounds__(256, 1) void k_bg(const unsigned short* __restrict__ xn,
                                               const float* __restrict__ Wb,
                                               const float* __restrict__ bb,
                                               const float* __restrict__ Wg,
                                               const float* __restrict__ bg,
                                               float* __restrict__ betab,
                                               float* __restrict__ gammab) {
    const int m = blockIdx.x;
    const int t = threadIdx.x;
    const int h = t >> 4, seg = t & 15;
    const ushort4* xr = (const ushort4*)(xn + (size_t)m * DMODEL + seg * 64);
    const float4* wbr = (const float4*)(Wb + (size_t)h * DMODEL + seg * 64);
    const float4* wgr = (const float4*)(Wg + (size_t)h * DMODEL + seg * 64);
    float db = 0.f, dg = 0.f;
#pragma unroll
    for (int u = 0; u < 16; u++) {
        ushort4 a = xr[u];
        float4 w1 = wbr[u], w2 = wgr[u];
        union { unsigned int i; float f; } c0, c1, c2, c3;
        c0.i = ((unsigned int)a.x) << 16; c1.i = ((unsigned int)a.y) << 16;
        c2.i = ((unsigned int)a.z) << 16; c3.i = ((unsigned int)a.w) << 16;
        db += c0.f * w1.x + c1.f * w1.y + c2.f * w1.z + c3.f * w1.w;
        dg += c0.f * w2.x + c1.f * w2.y + c2.f * w2.z + c3.f * w2.w;
    }
#pragma unroll
    for (int off = 1; off < 16; off <<= 1) {
        db += __shfl_xor(db, off);
        dg += __shfl_xor(dg, off);
    }
    if (seg == 0) {
        betab[(size_t)m * NH + h] = sigm(db + bb[h]);
        gammab[(size_t)m * NH + h] = sigm(dg + bg[h]);
    }
}

// ------------------------------------------- k normalization (in-place, fp16)
__global__ __launch_bounds__(256, 1) void k_prep(__half* __restrict__ kb) {
    const int row = blockIdx.x * 16 + (threadIdx.x >> 4);
    const int tr = threadIdx.x & 15;
    const int bh = row >> 11, t = row & 2047;
    const size_t idx = ((size_t)((bh >> 4) * T_SEQ + t)) * DMODEL + (bh & 15) * 64 + tr * 4;
    f16x4 k4 = *(const f16x4*)((const __half*)kb + idx);
    float k0 = (float)k4[0], k1 = (float)k4[1], k2 = (float)k4[2], k3 = (float)k4[3];
    float ss = k0 * k0 + k1 * k1 + k2 * k2 + k3 * k3;
    ss = rowsum16(ss);
    float inv = 1.f / fmaxf(sqrtf(ss), 1e-12f);
    f16x4 o;
    o[0] = (_Float16)(k0 * inv); o[1] = (_Float16)(k1 * inv);
    o[2] = (_Float16)(k2 * inv); o[3] = (_Float16)(k3 * inv);
    *(f16x4*)(kb + idx) = o;
}

// ------------------------------------------------------------- the scan
// 256 blocks = 64 (b,h) x 4 column-groups; 256 thr = 16 columns x 16 lanes.
// 6-slot register rotation: loads prefetch distance 6, cvt distance 1 ->
// load->use gap ~5 steps, hiding HBM-miss latency (~900 cyc).
__global__ __launch_bounds__(256, 1) void k_scan(const __half* __restrict__ qb,
                                                 const __half* __restrict__ knb,
                                                 const __half* __restrict__ vb,
                                                 const __half* __restrict__ ab,
                                                 const __half* __restrict__ aRb,
                                                 const float* __restrict__ betab,
                                                 const float* __restrict__ gammab,
                                                 unsigned short* __restrict__ ob) {
    const int blk = blockIdx.x;
    const int bh = blk >> 2, cg = blk & 3;
    const int b = bh >> 4, h = bh & 15;
    const int t = threadIdx.x;
    const int col = t >> 4, tr = t & 15;
    const int ii = cg * 16 + col;
    const int j0 = tr * 4;

    const size_t vecbase = ((size_t)b * T_SEQ) * DMODEL + h * 64 + j0;
    const size_t vbase = ((size_t)b * T_SEQ) * DMODEL + h * 64 + ii;
    const size_t bgbase = ((size_t)b * T_SEQ) * NH + h;

    const __half* pk = knb + vecbase;
    const __half* pq = qb + vecbase;
    const __half* pa = ab + vecbase;
    const __half* pr = aRb + vecbase;

    float S0 = 0, S1 = 0, S2 = 0, S3 = 0, R0 = 0, R1 = 0, R2 = 0, R3 = 0;

    f16x4 rk[6], rq[6], ra[6], rr[6];
    __half rv[6];
    float rbe[6], rga[6];
    f32x4 fkn[6], fq[6], fa[6], fr[6];
    float fv[6];

#pragma unroll
    for (int p = 0; p < 6; p++) {
        const size_t voff = (size_t)p * DMODEL;
        rk[p] = *(const f16x4*)(pk + voff);
        rq[p] = *(const f16x4*)(pq + voff);
        ra[p] = *(const f16x4*)(pa + voff);
        rr[p] = *(const f16x4*)(pr + voff);
        rv[p] = vb[vbase + voff];
        rbe[p] = betab[bgbase + (size_t)p * NH];
        rga[p] = gammab[bgbase + (size_t)p * NH];
    }
    fkn[0][0] = (float)rk[0][0]; fkn[0][1] = (float)rk[0][1]; fkn[0][2] = (float)rk[0][2]; fkn[0][3] = (float)rk[0][3];
    fq[0][0] = (float)rq[0][0]; fq[0][1] = (float)rq[0][1]; fq[0][2] = (float)rq[0][2]; fq[0][3] = (float)rq[0][3];
    fa[0][0] = (float)ra[0][0]; fa[0][1] = (float)ra[0][1]; fa[0][2] = (float)ra[0][2]; fa[0][3] = (float)ra[0][3];
    fr[0][0] = (float)rr[0][0]; fr[0][1] = (float)rr[0][1]; fr[0][2] = (float)rr[0][2]; fr[0][3] = (float)rr[0][3];
    fv[0] = (float)rv[0];

#define SCAN_BODY(P, PN)                                                              \
    {                                                                                 \
        const int s = st + (P);                                                       \
        const float beta = rbe[P], gamma = rga[P];                                    \
        /* prefetch step s+6 into slot P (its raw was cvt'd last body) */             \
        {                                                                             \
            const size_t voff = (size_t)((s + 6) & (T_SEQ - 1)) * DMODEL;             \
            rk[P] = *(const f16x4*)(pk + voff);                                       \
            rq[P] = *(const f16x4*)(pq + voff);                                       \
            ra[P] = *(const f16x4*)(pa + voff);                                       \
            rr[P] = *(const f16x4*)(pr + voff);                                       \
            rv[P] = vb[vbase + voff];                                                 \
            const size_t soff = (size_t)((s + 6) & (T_SEQ - 1)) * NH;                 \
            rbe[P] = betab[bgbase + soff];                                            \
            rga[P] = gammab[bgbase + soff];                                           \
        }                                                                             \
        /* cvt slot PN = step s+1 (loaded 5 bodies ago) */                            \
        fkn[PN][0] = (float)rk[PN][0]; fkn[PN][1] = (float)rk[PN][1];                 \
        fkn[PN][2] = (float)rk[PN][2]; fkn[PN][3] = (float)rk[PN][3];                 \
        fq[PN][0] = (float)rq[PN][0]; fq[PN][1] = (float)rq[PN][1];                   \
        fq[PN][2] = (float)rq[PN][2]; fq[PN][3] = (float)rq[PN][3];                   \
        fa[PN][0] = (float)ra[PN][0]; fa[PN][1] = (float)ra[PN][1];                   \
        fa[PN][2] = (float)ra[PN][2]; fa[PN][3] = (float)ra[PN][3];                   \
        fr[PN][0] = (float)rr[PN][0]; fr[PN][1] = (float)rr[PN][1];                   \
        fr[PN][2] = (float)rr[PN][2]; fr[PN][3] = (float)rr[PN][3];                   \
        fv[PN] = (float)rv[PN];                                                       \
        /* critical chain for step s, float set P */                                  \
        {                                                                             \
            const float kn0 = fkn[P][0], kn1 = fkn[P][1], kn2 = fkn[P][2], kn3 = fkn[P][3]; \
            const float a0 = fa[P][0], a1 = fa[P][1], a2 = fa[P][2], a3 = fa[P][3];   \
            const float x0 = fr[P][0], x1 = fr[P][1], x2 = fr[P][2], x3 = fr[P][3];   \
            const float vc = fv[P];                                                   \
            float pred = S0 * kn0 + S1 * kn1 + S2 * kn2 + S3 * kn3;                   \
            float Sd0 = a0 * S0, Sd1 = a1 * S1, Sd2 = a2 * S2, Sd3 = a3 * S3;         \
            float Rd0 = x0 * R0, Rd1 = x1 * R1, Rd2 = x2 * R2, Rd3 = x3 * R3;         \
            float kp = Sd0 * kn0 + Sd1 * kn1 + Sd2 * kn2 + Sd3 * kn3;                 \
            float kpR = Rd0 * kn0 + Rd1 * kn1 + Rd2 * kn2 + Rd3 * kn3;                \
            pred = rowsum16(pred);                                                    \
            kp = rowsum16(kp);                                                        \
            kpR = rowsum16(kpR);                                                      \
            const float rres = fminf(fmaxf(vc - pred, -1.f), 1.f);                    \
            const float cS = beta * (vc - kp);                                        \
            const float cR = gamma * (rres - kpR);                                    \
            S0 = fmaf(cS, kn0, Sd0); S1 = fmaf(cS, kn1, Sd1);                         \
            S2 = fmaf(cS, kn2, Sd2); S3 = fmaf(cS, kn3, Sd3);                         \
            R0 = fmaf(cR, kn0, Rd0); R1 = fmaf(cR, kn1, Rd1);                         \
            R2 = fmaf(cR, kn2, Rd2); R3 = fmaf(cR, kn3, Rd3);                         \
            float o = (S0 + R0) * fq[P][0] + (S1 + R1) * fq[P][1] +                   \
                      (S2 + R2) * fq[P][2] + (S3 + R3) * fq[P][3];                    \
            o = rowsum16(o);                                                          \
            if (tr == 0 && s < T_SEQ)                                                 \
                ob[vbase + (size_t)s * DMODEL] = f2bf(o);                             \
        }                                                                             \
    }

    for (int st = 0; st < T_SEQ; st += 6) {
        SCAN_BODY(0, 1)
        SCAN_BODY(1, 2)
        SCAN_BODY(2, 3)
        SCAN_BODY(3, 4)
        SCAN_BODY(4, 5)
        SCAN_BODY(5, 0)
    }
#undef SCAN_BODY
}

// ---------------------------------------------------- output GEMM + residual
__global__ __launch_bounds__(256, 1) void k_out(const unsigned short* __restrict__ ob,
                                                const unsigned short* __restrict__ wobf,
                                                const float* __restrict__ x,
                                                float* __restrict__ out) {
    const int m0 = blockIdx.x * 128;
    const int n0 = blockIdx.y * 128;
    f32x4 acc[4][4];
    gemm128<1024>(ob, wobf, m0, n0, acc);
    const int lane = threadIdx.x & 63;
    const int wv = threadIdx.x >> 6;
    const int wm = wv >> 1, wn = wv & 1;
    const int ml = lane & 15, kq = lane >> 4;
#pragma unroll
    for (int mt = 0; mt < 4; mt++)
#pragma unroll
        for (int nt = 0; nt < 4; nt++) {
            const int rowg = m0 + wm * 64 + mt * 16 + kq * 4;
            const int colg = n0 + wn * 64 + nt * 16 + ml;
#pragma unroll
            for (int r = 0; r < 4; r++) {
                size_t idx = (size_t)(rowg + r) * DMODEL + colg;
                out[idx] = acc[mt][nt][r] + x[idx];
            }
        }
}

extern "C" void kernel_launch(void* const* d_in, const int* in_sizes, int n_in,
                              void* d_out, int out_size, void* d_ws, size_t ws_size,
                              hipStream_t stream) {
    const float* x = (const float*)d_in[0];
    const float* Wq = (const float*)d_in[1];
    const float* Wk = (const float*)d_in[2];
    const float* Wv = (const float*)d_in[3];
    const float* Wa = (const float*)d_in[4];
    const float* ba = (const float*)d_in[5];
    const float* Wb = (const float*)d_in[6];
    const float* bb = (const float*)d_in[7];
    const float* Wg = (const float*)d_in[8];
    const float* bg = (const float*)d_in[9];
    const float* WaR = (const float*)d_in[10];
    const float* baR = (const float*)d_in[11];
    const float* Wo = (const float*)d_in[12];
    const float* lnw = (const float*)d_in[13];
    const float* lnb = (const float*)d_in[14];

    const size_t SZ = 16777216ULL;  // one fp16/bf16 plane (8192*1024*2 B)
    size_t need = 6 * SZ + 2 * 524288ULL;
    if (ws_size < need) return;

    char* ws = (char*)d_ws;
    __half* qb = (__half*)(ws + 0 * SZ);
    __half* kb = (__half*)(ws + 1 * SZ);
    __half* vb = (__half*)(ws + 2 * SZ);
    __half* ab = (__half*)(ws + 3 * SZ);
    __half* aRb = (__half*)(ws + 4 * SZ);
    unsigned short* xn = (unsigned short*)(ws + 5 * SZ);  // bf16; reused for o
    float* betab = (float*)(ws + 6 * SZ);
    float* gammab = (float*)(ws + 6 * SZ + 524288ULL);

    // d_out doubles as scratch for bf16 projection weights (10 MB of 32 MB);
    // it is only read by k_proj and fully overwritten by k_out at the end.
    unsigned short* wbf = (unsigned short*)d_out;
    // Wo-bf16 goes into the (dead after scan) qb plane.
    unsigned short* wobf = (unsigned short*)qb;

    WPtrs wp{Wq, Wk, Wv, Wa, WaR};
    k_wconv<<<dim3(512, 5), dim3(256), 0, stream>>>(wp, wbf);
    k_ln<<<dim3(MTOT), dim3(256), 0, stream>>>(x, lnw, lnb, xn);
    k_proj<<<dim3(64, 40), dim3(256), 0, stream>>>(xn, wbf, ba, baR, qb, kb, vb, ab, aRb);
    k_bg<<<dim3(MTOT), dim3(256), 0, stream>>>(xn, Wb, bb, Wg, bg, betab, gammab);
    k_prep<<<dim3(MTOT * NH / 16), dim3(256), 0, stream>>>(kb);  // kb -> kn in place
    // scan writes o (bf16) over xn (xn dead after k_proj/k_bg)
    k_scan<<<dim3(256), dim3(256), 0, stream>>>(qb, kb, vb, ab, aRb, betab, gammab, xn);
    k_cvt1<<<dim3(512), dim3(256), 0, stream>>>(Wo, wobf);  // qb dead after scan
    k_out<<<dim3(64, 8), dim3(256), 0, stream>>>(xn, wobf, x, (float*)d_out);
}